// Round 12
// baseline (695.368 us; speedup 1.0000x reference)
//
#include <hip/hip_runtime.h>
#include <hip/hip_bf16.h>
#include <math.h>

typedef __bf16 bf16;
typedef __attribute__((ext_vector_type(4))) __bf16 bf16x4;
typedef __attribute__((ext_vector_type(8))) __bf16 bf16x8;
typedef __attribute__((ext_vector_type(4))) float f32x4;

#define N_NODES 20000
#define N_EDGES 320000
#define E2 (N_EDGES + N_NODES)   // 340000 edges incl self-loops
#define F_IN 50
#define D1 1024                  // H1*C1
#define NP12 2048                // padded GEMM out-cols, layer 2 ([W|Wl])
#define NP3 896                  // padded GEMM out-cols, layer 3 (726+121=847 -> 896)
#define SG 2048                  // row stride of GEMM output buffer
#define KA 320                   // layer-1 fused K: 4*64 aggx + 64 x

// params pool element offsets (bf16 pool)
#define PO_A1S 0
#define PO_A1D 1024
#define PO_B1  2048
#define PO_BL1 3072
#define PO_A2S 4096
#define PO_A2D 5120
#define PO_B2  6144
#define PO_BL2 7168
#define PO_A3S 8192
#define PO_A3D 8918
#define PO_B3  9644
#define PO_BL3 9765
#define PO_END 9886

__device__ __forceinline__ int clampi(int v, int lo, int hi)
{
    return v < lo ? lo : (v > hi ? hi : v);
}

__device__ __forceinline__ float loadf(const void* p, long idx, int isb)
{
    return isb ? (float)((const bf16*)p)[idx] : ((const float*)p)[idx];
}

__device__ __forceinline__ int loadei(const int* ei, long idx, int i64)
{
    return i64 ? ei[2 * idx] : ei[idx];
}

// --------------------------------------------------------------- detect -----
__global__ void k_detect(const int* __restrict__ ei,
                         const unsigned short* __restrict__ xw,
                         int* __restrict__ flags)
{
    __shared__ int bad64, cexp;
    int t = threadIdx.x;
    if (t == 0) { bad64 = 0; cexp = 0; }
    __syncthreads();
    if (t < 128) {
        if (ei[2 * t + 1] != 0) atomicAdd(&bad64, 1);
    } else {
        int i = t - 128;
        int e = (xw[2 * i] >> 7) & 0xFF;
        if (e >= 100 && e <= 140) atomicAdd(&cexp, 1);
    }
    __syncthreads();
    if (t == 0) {
        flags[0] = (bad64 == 0) ? 1 : 0;
        flags[1] = (cexp >= 64) ? 1 : 0;
    }
}

// ---------------------------------------------------------------- GEMM ------
// m97-style 128x128 tile, BK=64, global_load_lds width-16, XCD swizzle,
// XOR k-chunk LDS swizzle. BACT: fused bias+ELU epilogue (bf16 out).
// F32OUT: write f32 to C at row*ldc+col for col<ldc (tall-skinny logits).
template <bool BACT, bool F32OUT>
__global__ __launch_bounds__(256) void k_gemm(const bf16* __restrict__ A,
                                              const bf16* __restrict__ Bt,
                                              bf16* __restrict__ C,
                                              int M, int K, int lda, int ldb, int ldc,
                                              int mtiles, int ntiles,
                                              const bf16* __restrict__ bias)
{
    __shared__ bf16 As[128 * 64];
    __shared__ bf16 Bs[128 * 64];

    int id = blockIdx.x;
    int gfull = mtiles >> 3;
    int base  = gfull * 8 * ntiles;
    int x, y;
    if (id < base) {
        int gsz = 8 * ntiles;
        int g = id / gsz;
        int r = id - g * gsz;
        x = g * 8 + (r & 7);
        y = r >> 3;
    } else {
        int rem = mtiles - (gfull << 3);
        int r = id - base;
        x = (gfull << 3) + r % rem;
        y = r / rem;
    }
    const int m0 = x * 128;
    const int n0 = y * 128;

    const int tid  = threadIdx.x;
    const int wave = tid >> 6;
    const int lane = tid & 63;
    const int wm   = (wave >> 1) * 64;
    const int wn   = (wave & 1) * 64;
    const int frow  = lane & 15;

    const int srow = wave * 32 + (lane >> 3);
    const int scol = (((lane & 7) ^ (lane >> 3)) * 8);

    f32x4 acc[4][4];
#pragma unroll
    for (int i = 0; i < 4; ++i)
#pragma unroll
        for (int j = 0; j < 4; ++j)
#pragma unroll
            for (int r = 0; r < 4; ++r) acc[i][j][r] = 0.f;

    for (int k0 = 0; k0 < K; k0 += 64) {
#pragma unroll
        for (int i = 0; i < 4; ++i) {
            int ra = srow + i * 8;
            int ga = m0 + ra; if (ga > M - 1) ga = M - 1;   // junk rows -> discarded C rows
            __builtin_amdgcn_global_load_lds(
                (const __attribute__((address_space(1))) void*)(A + (size_t)ga * lda + k0 + scol),
                (__attribute__((address_space(3))) void*)(As + wave * 2048 + i * 512),
                16, 0, 0);
            int gb = n0 + ra;
            __builtin_amdgcn_global_load_lds(
                (const __attribute__((address_space(1))) void*)(Bt + (size_t)gb * ldb + k0 + scol),
                (__attribute__((address_space(3))) void*)(Bs + wave * 2048 + i * 512),
                16, 0, 0);
        }
        __syncthreads();
#pragma unroll
        for (int kk = 0; kk < 2; ++kk) {
            const int coff = (((kk * 4 + (lane >> 4)) ^ (frow & 7)) << 3);
            bf16x8 af[4], bfr[4];
#pragma unroll
            for (int i = 0; i < 4; ++i) {
                af[i]  = *(const bf16x8*)(As + (wm + i * 16 + frow) * 64 + coff);
                bfr[i] = *(const bf16x8*)(Bs + (wn + i * 16 + frow) * 64 + coff);
            }
#pragma unroll
            for (int i = 0; i < 4; ++i)
#pragma unroll
                for (int j = 0; j < 4; ++j)
                    acc[i][j] = __builtin_amdgcn_mfma_f32_16x16x32_bf16(af[i], bfr[j], acc[i][j], 0, 0, 0);
        }
        __syncthreads();
    }

#pragma unroll
    for (int i = 0; i < 4; ++i) {
#pragma unroll
        for (int j = 0; j < 4; ++j) {
            int rbase = m0 + wm + i * 16 + (lane >> 4) * 4;
            int col   = n0 + wn + j * 16 + frow;
            if constexpr (F32OUT) {
                if (col < ldc) {
#pragma unroll
                    for (int r = 0; r < 4; ++r) {
                        int row = rbase + r;
                        if (row < M) ((float*)C)[(size_t)row * ldc + col] = acc[i][j][r];
                    }
                }
            } else if constexpr (BACT) {
                float bv = (float)bias[col];
#pragma unroll
                for (int r = 0; r < 4; ++r) {
                    int row = rbase + r;
                    if (row < M) {
                        float v = acc[i][j][r] + bv;
                        v = (v > 0.f) ? v : (expf(v) - 1.f);
                        C[(size_t)row * ldc + col] = (bf16)v;
                    }
                }
            } else {
#pragma unroll
                for (int r = 0; r < 4; ++r) {
                    int row = rbase + r;
                    if (row < M) C[(size_t)row * ldc + col] = (bf16)acc[i][j][r];
                }
            }
        }
    }
}

// ------------------------------------------------------------ prep kernels --
// x -> A2[n*KA + 256 + k] (padded to 64)
__global__ void k_padx(const void* __restrict__ x, bf16* __restrict__ A2,
                       const int* __restrict__ flags)
{
    int idx = blockIdx.x * 256 + threadIdx.x;
    if (idx >= N_NODES * 64) return;
    int isb = flags[1];
    int n = idx >> 6, k = idx & 63;
    A2[(size_t)n * KA + 256 + k] = (k < F_IN) ? (bf16)loadf(x, (long)n * F_IN + k, isb)
                                              : (bf16)0.f;
}

// ws[k][h] = sum_c W1[k, h*256+c]*a1s[h,c]; wd likewise; bsum = b1+bl1.
__global__ __launch_bounds__(256) void k_veca(const void* __restrict__ W1,
                                              const void* __restrict__ a1s,
                                              const void* __restrict__ a1d,
                                              const void* __restrict__ b1,
                                              const void* __restrict__ bl1,
                                              float* __restrict__ ws, float* __restrict__ wd,
                                              bf16* __restrict__ bsum,
                                              const int* __restrict__ flags)
{
    const int isb = flags[1];
    const int k = blockIdx.x;          // 0..63
    const int h = threadIdx.x >> 6;
    const int c0 = threadIdx.x & 63;
    float s = 0.f, d = 0.f;
    if (k < F_IN) {
        for (int c = c0; c < 256; c += 64) {
            float wv = loadf(W1, (long)k * D1 + h * 256 + c, isb);
            s += wv * loadf(a1s, h * 256 + c, isb);
            d += wv * loadf(a1d, h * 256 + c, isb);
        }
    }
#pragma unroll
    for (int off = 32; off; off >>= 1) {
        s += __shfl_xor(s, off);
        d += __shfl_xor(d, off);
    }
    if (c0 == 0) { ws[k * 4 + h] = s; wd[k * 4 + h] = d; }
    if (k < 4) {
        int j = k * 256 + threadIdx.x;
        bsum[j] = (bf16)(loadf(b1, j, isb) + loadf(bl1, j, isb));
    }
}

// BtL3 row h (0..5) = W3^T a3s head-proj; rows 6..11 = a3d. Block per k.
__global__ __launch_bounds__(256) void k_veca3(const void* __restrict__ W3,
                                               const void* __restrict__ a3s,
                                               const void* __restrict__ a3d,
                                               bf16* __restrict__ BtL3,
                                               const int* __restrict__ flags)
{
    __shared__ float srs[726], srd[726];
    const int isb = flags[1];
    const int k = blockIdx.x;    // 0..1023
    for (int t = threadIdx.x; t < 726; t += 256) {
        float wv = loadf(W3, (long)k * 726 + t, isb);
        srs[t] = wv * loadf(a3s, t, isb);   // a3s flat [6][121]
        srd[t] = wv * loadf(a3d, t, isb);
    }
    __syncthreads();
    int t = threadIdx.x;
    if (t < 6) {
        float s = 0.f;
        for (int c = 0; c < 121; ++c) s += srs[t * 121 + c];
        BtL3[(size_t)t * 1024 + k] = (bf16)s;
    } else if (t >= 64 && t < 70) {
        int h = t - 64;
        float d = 0.f;
        for (int c = 0; c < 121; ++c) d += srd[h * 121 + c];
        BtL3[(size_t)(6 + h) * 1024 + k] = (bf16)d;
    }
}

// BtL2 [128 x 1024]: row h (0..3) col h*256+c = a2s[h][c]; rows 4..7 = a2d.
__global__ void k_vecb2(const bf16* __restrict__ pool, bf16* __restrict__ BtL2)
{
    int idx = blockIdx.x * 256 + threadIdx.x;   // 0..1023 == h*256+c
    if (idx >= 1024) return;
    int h = idx >> 8;
    BtL2[(size_t)h * 1024 + idx]       = pool[PO_A2S + idx];
    BtL2[(size_t)(4 + h) * 1024 + idx] = pool[PO_A2D + idx];
}

// fused layer-1 B^T [1024 x KA]: k'<256 blockdiag(W1), k'>=256 Wl1
__global__ void k_wfuse1(const void* __restrict__ W1, const void* __restrict__ Wl1,
                         bf16* __restrict__ Bt, const int* __restrict__ flags)
{
    int idx = blockIdx.x * 256 + threadIdx.x;
    if (idx >= D1 * KA) return;
    int isb = flags[1];
    int j = idx / KA;
    int kp = idx - j * KA;
    float v = 0.f;
    if (kp < 256) {
        int hp = kp >> 6, k = kp & 63;
        if ((j >> 8) == hp && k < F_IN) v = loadf(W1, (long)k * D1 + j, isb);
    } else {
        int k = kp - 256;
        if (k < F_IN) v = loadf(Wl1, (long)k * D1 + j, isb);
    }
    Bt[idx] = (bf16)v;
}

// Tiled transpose-concat: Bt[n][k] = [Wa | Wb | 0](k, n), K=1024 rows.
__global__ __launch_bounds__(256) void k_wcatT(const void* __restrict__ Wa,
                                               const void* __restrict__ Wb,
                                               bf16* __restrict__ Bt,
                                               int split, int da, int db,
                                               const int* __restrict__ flags)
{
    __shared__ bf16 T[64][65];
    const int isb = flags[1];
    const int k0 = blockIdx.x * 64;
    const int n0 = blockIdx.y * 64;
    const int r = threadIdx.x >> 6;    // 0..3
    const int c = threadIdx.x & 63;
    const int n = n0 + c;
#pragma unroll
    for (int kk = 0; kk < 16; ++kk) {
        int k = k0 + r + kk * 4;
        float v = 0.f;
        if (n < split)           v = loadf(Wa, (long)k * da + n, isb);
        else if (n < split + db) v = loadf(Wb, (long)k * db + (n - split), isb);
        T[r + kk * 4][c] = (bf16)v;
    }
    __syncthreads();
#pragma unroll
    for (int kk = 0; kk < 16; ++kk) {
        int nn = r + kk * 4;
        Bt[(size_t)(n0 + nn) * 1024 + k0 + c] = T[c][nn];
    }
}

struct P12 { const void* s[12]; };

__global__ void k_params(P12 ps, bf16* __restrict__ pool, const int* __restrict__ flags)
{
    const int off[13] = {PO_A1S, PO_A1D, PO_B1, PO_BL1, PO_A2S, PO_A2D, PO_B2,
                         PO_BL2, PO_A3S, PO_A3D, PO_B3, PO_BL3, PO_END};
    int idx = blockIdx.x * 256 + threadIdx.x;
    if (idx >= PO_END) return;
    int isb = flags[1];
    int seg = 0;
    while (idx >= off[seg + 1]) seg++;
    pool[idx] = (bf16)loadf(ps.s[seg], idx - off[seg], isb);
}

// ------------------------------------------------------------- CSR build ----
__global__ void k_count(const int* __restrict__ ei, int* __restrict__ cnt,
                        const int* __restrict__ flags)
{
    int e = blockIdx.x * 256 + threadIdx.x;
    if (e >= E2) return;
    int i64 = flags[0];
    int d = (e < N_EDGES) ? loadei(ei, (long)N_EDGES + e, i64) : (e - N_EDGES);
    d = clampi(d, 0, N_NODES - 1);
    atomicAdd(&cnt[d], 1);
}

__global__ __launch_bounds__(256) void k_scan(const int* __restrict__ cnt,
                                              int* __restrict__ rp, int* __restrict__ cur)
{
    __shared__ int ssum[256];
    int tid = threadIdx.x;
    const int chunk = (N_NODES + 255) / 256;
    int lo = tid * chunk;
    int hi = lo + chunk; if (hi > N_NODES) hi = N_NODES;
    int s = 0;
    for (int i = lo; i < hi; ++i) s += cnt[i];
    ssum[tid] = s;
    __syncthreads();
    if (tid == 0) {
        int run = 0;
        for (int i = 0; i < 256; ++i) { int t = ssum[i]; ssum[i] = run; run += t; }
        rp[N_NODES] = run;
    }
    __syncthreads();
    int run = ssum[tid];
    for (int i = lo; i < hi; ++i) {
        rp[i] = run; cur[i] = run;
        run += cnt[i];
    }
}

__global__ void k_fill(const int* __restrict__ ei, int* __restrict__ cur,
                       int* __restrict__ ss, const int* __restrict__ flags)
{
    int e = blockIdx.x * 256 + threadIdx.x;
    if (e >= E2) return;
    int i64 = flags[0];
    int s, d;
    if (e < N_EDGES) {
        s = loadei(ei, e, i64);
        d = loadei(ei, (long)N_EDGES + e, i64);
    } else {
        s = e - N_EDGES; d = s;
    }
    s = clampi(s, 0, N_NODES - 1);
    d = clampi(d, 0, N_NODES - 1);
    int pos = atomicAdd(&cur[d], 1);
    if (pos >= 0 && pos < E2) ss[pos] = s;
}

// ----------------------------------------------------- attention kernels ----
// layer-1 logits: es[n,h] = sum_k x[n,k]*ws[k,h] (wave per node)
__global__ __launch_bounds__(256) void k_logits1(const bf16* __restrict__ A2,
                                                 const float* __restrict__ ws,
                                                 const float* __restrict__ wd,
                                                 float* __restrict__ es, float* __restrict__ ed)
{
    const int wave = threadIdx.x >> 6;
    const int lane = threadIdx.x & 63;
    const int n = blockIdx.x * 4 + wave;
    if (n >= N_NODES) return;
    float xv = (float)A2[(size_t)n * KA + 256 + lane];
    f32x4 wsv = *(const f32x4*)(ws + lane * 4);
    f32x4 wdv = *(const f32x4*)(wd + lane * 4);
    float s[4], d[4];
#pragma unroll
    for (int h = 0; h < 4; ++h) { s[h] = xv * wsv[h]; d[h] = xv * wdv[h]; }
#pragma unroll
    for (int off = 32; off; off >>= 1)
#pragma unroll
        for (int h = 0; h < 4; ++h) {
            s[h] += __shfl_xor(s[h], off);
            d[h] += __shfl_xor(d[h], off);
        }
    if (lane == 0) {
#pragma unroll
        for (int h = 0; h < 4; ++h) { es[n * 4 + h] = s[h]; ed[n * 4 + h] = d[h]; }
    }
}

// layer-1 aggregate: aggx[n,h,k] = sum_e alpha[e,h] x[src_e,k] (block per node)
__global__ __launch_bounds__(256) void k_aggx(bf16* __restrict__ A2,
                                              const float* __restrict__ es,
                                              const float* __restrict__ ed,
                                              const int* __restrict__ rp,
                                              const int* __restrict__ ss)
{
    __shared__ float smx[4], sinv[4], sed[4];
    __shared__ float sal[64 * 4];
    __shared__ int   ssrc[64];

    const int n   = blockIdx.x;
    const int tid = threadIdx.x;
    int r0 = clampi(rp[n], 0, E2);
    int r1 = clampi(rp[n + 1], r0, E2);
    const int deg = r1 - r0;

    const int sw = tid >> 5, ln = tid & 31;
    if (sw < 4) {
        int h = sw;
        float edn = ed[n * 4 + h];
        float mx = -1e30f;
        for (int e = ln; e < deg; e += 32) {
            int s = clampi(ss[r0 + e], 0, N_NODES - 1);
            float w = es[s * 4 + h] + edn;
            w = (w > 0.f) ? w : 0.2f * w;
            mx = fmaxf(mx, w);
        }
#pragma unroll
        for (int off = 16; off; off >>= 1) mx = fmaxf(mx, __shfl_xor(mx, off, 32));
        float sm = 0.f;
        for (int e = ln; e < deg; e += 32) {
            int s = clampi(ss[r0 + e], 0, N_NODES - 1);
            float w = es[s * 4 + h] + edn;
            w = (w > 0.f) ? w : 0.2f * w;
            sm += expf(w - mx);
        }
#pragma unroll
        for (int off = 16; off; off >>= 1) sm += __shfl_xor(sm, off, 32);
        if (ln == 0) { smx[h] = mx; sinv[h] = 1.f / fmaxf(sm, 1e-16f); sed[h] = edn; }
    }
    __syncthreads();

    const int k  = tid & 63;
    const int hh = tid >> 6;
    float acc = 0.f;

    for (int e0 = 0; e0 < deg; e0 += 64) {
        int ce = min(64, deg - e0);
        __syncthreads();
        if (tid < ce * 4) {
            int e = tid >> 2, h = tid & 3;
            int s = clampi(ss[r0 + e0 + e], 0, N_NODES - 1);
            float w = es[s * 4 + h] + sed[h];
            w = (w > 0.f) ? w : 0.2f * w;
            sal[e * 4 + h] = expf(w - smx[h]) * sinv[h];
            if (h == 0) ssrc[e] = s;
        }
        __syncthreads();
        for (int e = 0; e < ce; ++e) {
            int s = ssrc[e];
            float xv = (float)A2[(size_t)s * KA + 256 + k];
            acc += sal[e * 4 + hh] * xv;
        }
    }
    A2[(size_t)n * KA + hh * 64 + k] = (bf16)acc;
}

// Fused per-dst-node softmax + gather-aggregate + bias + skip (+mean/ELU).
// Phase 2: 8-wide edge grouping (zero-padded alpha tail) -> 8 loads in flight.
// est: element stride of es/ed rows.
template <int H, int C, bool MEAN, bool ELU, bool EXTOUT>
__global__ __launch_bounds__(256) void k_agg(const bf16* __restrict__ G,
                                             const bf16* __restrict__ S,
                                             const float* __restrict__ es,
                                             const float* __restrict__ ed,
                                             const int* __restrict__ rp,
                                             const int* __restrict__ ss,
                                             const bf16* __restrict__ bgat,
                                             const bf16* __restrict__ bskip,
                                             void* __restrict__ out, int sout,
                                             const int* __restrict__ flags, int est)
{
    constexpr int D  = H * C;
    constexpr int NV = (D + 3) / 4;
    constexpr int CH = 256;
    __shared__ float smx[H], sinv[H], sed[H];
    __shared__ float sal[CH * H];
    __shared__ int   ssrc[CH];

    const int n   = blockIdx.x;
    const int tid = threadIdx.x;
    int r0 = clampi(rp[n], 0, E2);
    int r1 = clampi(rp[n + 1], r0, E2);
    const int deg = r1 - r0;

    const int sw = tid >> 5, ln = tid & 31;
    for (int h = sw; h < H; h += 8) {
        float edn = ed[n * est + h];
        float mx = -1e30f;
        for (int e = ln; e < deg; e += 32) {
            int s = clampi(ss[r0 + e], 0, N_NODES - 1);
            float w = es[s * est + h] + edn;
            w = (w > 0.f) ? w : 0.2f * w;
            mx = fmaxf(mx, w);
        }
#pragma unroll
        for (int off = 16; off; off >>= 1) mx = fmaxf(mx, __shfl_xor(mx, off, 32));
        float sm = 0.f;
        for (int e = ln; e < deg; e += 32) {
            int s = clampi(ss[r0 + e], 0, N_NODES - 1);
            float w = es[s * est + h] + edn;
            w = (w > 0.f) ? w : 0.2f * w;
            sm += expf(w - mx);
        }
#pragma unroll
        for (int off = 16; off; off >>= 1) sm += __shfl_xor(sm, off, 32);
        if (ln == 0) { smx[h] = mx; sinv[h] = 1.f / fmaxf(sm, 1e-16f); sed[h] = edn; }
    }
    __syncthreads();

    const int c0 = tid * 4;
    const int hA = (c0 < D) ? (c0 / C) : 0;
    const int hB = (c0 + 3 < D) ? ((c0 + 3) / C) : hA;
    int hj1 = ((c0 + 1 < D) ? ((c0 + 1) / C) : hA) == hA;
    int hj2 = ((c0 + 2 < D) ? ((c0 + 2) / C) : hA) == hA;
    const bool active = (tid < NV);

    float acc[4] = {0.f, 0.f, 0.f, 0.f};

    for (int e0 = 0; e0 < deg; e0 += CH) {
        int ce = min(CH, deg - e0);
        int ce8 = (ce + 7) & ~7;   // zero-padded to 8
        __syncthreads();
        for (int t = tid; t < ce8 * H; t += 256) {
            int e = t / H, h = t - e * H;
            if (e < ce) {
                int s = clampi(ss[r0 + e0 + e], 0, N_NODES - 1);
                float w = es[s * est + h] + sed[h];
                w = (w > 0.f) ? w : 0.2f * w;
                sal[e * H + h] = expf(w - smx[h]) * sinv[h];
                if (h == 0) ssrc[e] = s;
            } else {
                sal[e * H + h] = 0.f;
                if (h == 0) ssrc[e] = 0;
            }
        }
        __syncthreads();
        if (active) {
            for (int eb = 0; eb < ce8; eb += 8) {
                int sg[8];
#pragma unroll
                for (int p = 0; p < 8; ++p) sg[p] = ssrc[eb + p];
                bf16x4 g[8];
#pragma unroll
                for (int p = 0; p < 8; ++p)
                    g[p] = *(const bf16x4*)(G + (size_t)sg[p] * SG + c0);
                if constexpr (C % 4 == 0) {
                    float a[8];
#pragma unroll
                    for (int p = 0; p < 8; ++p) a[p] = sal[(eb + p) * H + hA];
#pragma unroll
                    for (int p = 0; p < 8; ++p)
#pragma unroll
                        for (int j = 0; j < 4; ++j)
                            acc[j] += a[p] * (float)g[p][j];
                } else {
                    float aL[8], aH[8];
#pragma unroll
                    for (int p = 0; p < 8; ++p) {
                        aL[p] = sal[(eb + p) * H + hA];
                        aH[p] = sal[(eb + p) * H + hB];
                    }
#pragma unroll
                    for (int p = 0; p < 8; ++p) {
                        acc[0] += aL[p] * (float)g[p][0];
                        acc[1] += (hj1 ? aL[p] : aH[p]) * (float)g[p][1];
                        acc[2] += (hj2 ? aL[p] : aH[p]) * (float)g[p][2];
                        acc[3] += aH[p] * (float)g[p][3];
                    }
                }
            }
        }
    }

    const int outbf = EXTOUT ? flags[1] : 1;

    if constexpr (!MEAN) {
        if (active) {
            bf16x4 bg = *(const bf16x4*)(bgat + c0);
            bf16x4 sk = *(const bf16x4*)(S + (size_t)n * SG + c0);
            bf16x4 bs = *(const bf16x4*)(bskip + c0);
            bf16x4 ov;
#pragma unroll
            for (int j = 0; j < 4; ++j) {
                float v = acc[j] + (float)bg[j] + (float)sk[j] + (float)bs[j];
                if (ELU) v = (v > 0.f) ? v : (expf(v) - 1.f);
                ov[j] = (bf16)v;
            }
            *(bf16x4*)((bf16*)out + (size_t)n * sout + c0) = ov;
        }
    } else {
        __shared__ float sagg[D];
        if (active) {
#pragma unroll
            for (int j = 0; j < 4; ++j) {
                int c = c0 + j;
                if (c < D) sagg[c] = acc[j];
            }
        }
        __syncthreads();
        for (int c = tid; c < C; c += 256) {
            float v = 0.f;
#pragma unroll
            for (int h = 0; h < H; ++h) v += sagg[h * C + c];
            v *= (1.f / H);
            v += (float)bgat[c] + (float)S[(size_t)n * SG + c] + (float)bskip[c];
            if (outbf) ((bf16*)out)[(size_t)n * sout + c] = (bf16)v;
            else       ((float*)out)[(size_t)n * sout + c] = v;
        }
    }
}

// ----------------------------------------------------------------- launch ---
extern "C" void kernel_launch(void* const* d_in, const int* in_sizes, int n_in,
                              void* d_out, int out_size, void* d_ws, size_t ws_size,
                              hipStream_t stream)
{
    const void* x   = d_in[0];
    const int*  ei  = (const int*)d_in[1];
    const void* W1  = d_in[2];
    const void* Wl1 = d_in[6];
    const void* W2  = d_in[8];
    const void* Wl2 = d_in[12];
    const void* W3  = d_in[14];
    const void* Wl3 = d_in[18];

    P12 ps;
    ps.s[0] = d_in[3];  ps.s[1] = d_in[4];  ps.s[2] = d_in[5];  ps.s[3] = d_in[7];
    ps.s[4] = d_in[9];  ps.s[5] = d_in[10]; ps.s[6] = d_in[11]; ps.s[7] = d_in[13];
    ps.s[8] = d_in[15]; ps.s[9] = d_in[16]; ps.s[10] = d_in[17]; ps.s[11] = d_in[19];

    char* w = (char*)d_ws;
    auto alloc = [&](size_t bytes) {
        char* p = w;
        w += (bytes + 255) & ~(size_t)255;
        return p;
    };
    int*   flags = (int*)alloc(64);
    int*   cnt   = (int*)alloc((size_t)N_NODES * 4);
    int*   rp    = (int*)alloc((size_t)(N_NODES + 1) * 4);
    int*   cur   = (int*)alloc((size_t)N_NODES * 4);
    int*   ss    = (int*)alloc((size_t)E2 * 4);
    float* esA   = (float*)alloc((size_t)N_NODES * 4 * 4);   // L1 (H=4)
    float* edA   = (float*)alloc((size_t)N_NODES * 4 * 4);
    float* esedB = (float*)alloc((size_t)N_NODES * 8 * 4);   // L2 [es(4)|ed(4)]
    float* esed3 = (float*)alloc((size_t)N_NODES * 12 * 4);  // L3 [es(6)|ed(6)]
    bf16*  pool  = (bf16*)alloc((size_t)PO_END * 2);
    float* ws1   = (float*)alloc((size_t)64 * 4 * 4);
    float* wd1   = (float*)alloc((size_t)64 * 4 * 4);
    bf16*  BtL3  = (bf16*)alloc((size_t)128 * 1024 * 2);
    bf16*  BtL2  = (bf16*)alloc((size_t)128 * 1024 * 2);
    bf16*  bsum  = (bf16*)alloc((size_t)D1 * 2);
    bf16*  Bt    = (bf16*)alloc((size_t)NP12 * 1024 * 2);
    bf16*  X     = (bf16*)alloc((size_t)N_NODES * D1 * 2);   // x1/x2
    bf16*  WS    = (bf16*)alloc((size_t)N_NODES * SG * 2);   // GEMM out [gat|skip]
    bf16*  A2    = WS;   // layer-1 A'' [N x KA] aliases WS (dead during layer 1)

    k_detect<<<1, 256, 0, stream>>>(ei, (const unsigned short*)x, flags);

    hipMemsetAsync(cnt, 0, N_NODES * 4, stream);
    k_count<<<(E2 + 255) / 256, 256, 0, stream>>>(ei, cnt, flags);
    k_scan<<<1, 256, 0, stream>>>(cnt, rp, cur);
    k_fill<<<(E2 + 255) / 256, 256, 0, stream>>>(ei, cur, ss, flags);

    k_params<<<(PO_END + 255) / 256, 256, 0, stream>>>(ps, pool, flags);
    hipMemsetAsync(BtL3, 0, (size_t)128 * 1024 * 2, stream);
    hipMemsetAsync(BtL2, 0, (size_t)128 * 1024 * 2, stream);
    k_veca3<<<D1, 256, 0, stream>>>(W3, ps.s[8], ps.s[9], BtL3, flags);
    k_vecb2<<<4, 256, 0, stream>>>(pool, BtL2);

    const dim3 blk(256);
    const int MT = (N_NODES + 127) / 128;   // 157

    // ---- layer 1 (restructured): aggregate x, then fused GEMM K=320
    k_veca<<<64, 256, 0, stream>>>(W1, ps.s[0], ps.s[1], ps.s[2], ps.s[3],
                                   ws1, wd1, bsum, flags);
    k_padx<<<(N_NODES * 64 + 255) / 256, 256, 0, stream>>>(x, A2, flags);
    k_wfuse1<<<(D1 * KA + 255) / 256, 256, 0, stream>>>(W1, Wl1, Bt, flags);
    k_logits1<<<N_NODES / 4, 256, 0, stream>>>(A2, ws1, wd1, esA, edA);
    k_aggx<<<N_NODES, 256, 0, stream>>>(A2, esA, edA, rp, ss);
    k_gemm<true, false><<<MT * (D1 / 128), blk, 0, stream>>>(
        A2, Bt, X, N_NODES, KA, KA, KA, D1, MT, D1 / 128, bsum);   // x1 = ELU(...)

    // ---- layer 2: K=1024, out 2048 = [GAT 1024 | skip 1024]
    k_wcatT<<<dim3(16, NP12 / 64), blk, 0, stream>>>(W2, Wl2, Bt, 1024, 1024, 1024, flags);
    k_gemm<false, false><<<MT * (NP12 / 128), blk, 0, stream>>>(
        X, Bt, WS, N_NODES, 1024, 1024, 1024, SG, MT, NP12 / 128, nullptr);
    // esB/edB = h2 @ [a2s|a2d blockdiag]: tall-skinny MFMA GEMM, f32 out cols<8
    k_gemm<false, true><<<MT, blk, 0, stream>>>(
        WS, BtL2, (bf16*)esedB, N_NODES, 1024, SG, 1024, 8, MT, 1, nullptr);
    k_agg<4, 256, false, true, false><<<N_NODES, 256, 0, stream>>>(
        WS, WS + D1, esedB, esedB + 4, rp, ss, pool + PO_B2, pool + PO_BL2,
        X, D1, flags, 8);

    // ---- layer 3: K=1024, out 896 = [GAT 726 | skip 121 | pad]
    k_wcatT<<<dim3(16, NP3 / 64), blk, 0, stream>>>(W3, Wl3, Bt, 726, 726, 121, flags);
    k_gemm<false, false><<<MT * (NP3 / 128), blk, 0, stream>>>(
        X, Bt, WS, N_NODES, 1024, 1024, 1024, SG, MT, NP3 / 128, nullptr);
    // es3/ed3 = x2 @ [vs3|vd3]: tall-skinny MFMA GEMM, f32 out cols<12
    k_gemm<false, true><<<MT, blk, 0, stream>>>(
        X, BtL3, (bf16*)esed3, N_NODES, 1024, 1024, 1024, 12, MT, 1, nullptr);
    k_agg<6, 121, true, false, true><<<N_NODES, 256, 0, stream>>>(
        WS, WS + 726, esed3, esed3 + 6, rp, ss, pool + PO_B3, pool + PO_BL3,
        d_out, 121, flags, 12);
}

// Round 13
// 662.098 us; speedup vs baseline: 1.0502x; 1.0502x over previous
//
#include <hip/hip_runtime.h>
#include <hip/hip_bf16.h>
#include <math.h>

typedef __bf16 bf16;
typedef __attribute__((ext_vector_type(4))) __bf16 bf16x4;
typedef __attribute__((ext_vector_type(8))) __bf16 bf16x8;
typedef __attribute__((ext_vector_type(4))) float f32x4;

#define N_NODES 20000
#define N_EDGES 320000
#define E2 (N_EDGES + N_NODES)   // 340000 edges incl self-loops
#define F_IN 50
#define D1 1024                  // H1*C1
#define NP12 2048                // padded GEMM out-cols, layer 2 ([W|Wl])
#define NP3 896                  // padded GEMM out-cols, layer 3 (726+121=847 -> 896)
#define SG 2048                  // row stride of GEMM output buffer
#define KA 320                   // layer-1 fused K: 4*64 aggx + 64 x

// params pool element offsets (bf16 pool)
#define PO_A1S 0
#define PO_A1D 1024
#define PO_B1  2048
#define PO_BL1 3072
#define PO_A2S 4096
#define PO_A2D 5120
#define PO_B2  6144
#define PO_BL2 7168
#define PO_A3S 8192
#define PO_A3D 8918
#define PO_B3  9644
#define PO_BL3 9765
#define PO_END 9886

__device__ __forceinline__ int clampi(int v, int lo, int hi)
{
    return v < lo ? lo : (v > hi ? hi : v);
}

__device__ __forceinline__ float loadf(const void* p, long idx, int isb)
{
    return isb ? (float)((const bf16*)p)[idx] : ((const float*)p)[idx];
}

__device__ __forceinline__ int loadei(const int* ei, long idx, int i64)
{
    return i64 ? ei[2 * idx] : ei[idx];
}

// --------------------------------------------------------------- detect -----
__global__ void k_detect(const int* __restrict__ ei,
                         const unsigned short* __restrict__ xw,
                         int* __restrict__ flags)
{
    __shared__ int bad64, cexp;
    int t = threadIdx.x;
    if (t == 0) { bad64 = 0; cexp = 0; }
    __syncthreads();
    if (t < 128) {
        if (ei[2 * t + 1] != 0) atomicAdd(&bad64, 1);
    } else {
        int i = t - 128;
        int e = (xw[2 * i] >> 7) & 0xFF;
        if (e >= 100 && e <= 140) atomicAdd(&cexp, 1);
    }
    __syncthreads();
    if (t == 0) {
        flags[0] = (bad64 == 0) ? 1 : 0;
        flags[1] = (cexp >= 64) ? 1 : 0;
    }
}

// ---------------------------------------------------------------- GEMM ------
// m97-style 128x128 tile, BK=64, global_load_lds width-16, XCD swizzle,
// XOR k-chunk LDS swizzle. BACT (compile-time): fused bias+ELU epilogue.
template <bool BACT>
__global__ __launch_bounds__(256) void k_gemm(const bf16* __restrict__ A,
                                              const bf16* __restrict__ Bt,
                                              bf16* __restrict__ C,
                                              int M, int K, int lda, int ldb, int ldc,
                                              int mtiles, int ntiles,
                                              const bf16* __restrict__ bias)
{
    __shared__ bf16 As[128 * 64];
    __shared__ bf16 Bs[128 * 64];

    int id = blockIdx.x;
    int gfull = mtiles >> 3;
    int base  = gfull * 8 * ntiles;
    int x, y;
    if (id < base) {
        int gsz = 8 * ntiles;
        int g = id / gsz;
        int r = id - g * gsz;
        x = g * 8 + (r & 7);
        y = r >> 3;
    } else {
        int rem = mtiles - (gfull << 3);
        int r = id - base;
        x = (gfull << 3) + r % rem;
        y = r / rem;
    }
    const int m0 = x * 128;
    const int n0 = y * 128;

    const int tid  = threadIdx.x;
    const int wave = tid >> 6;
    const int lane = tid & 63;
    const int wm   = (wave >> 1) * 64;
    const int wn   = (wave & 1) * 64;
    const int frow  = lane & 15;

    const int srow = wave * 32 + (lane >> 3);
    const int scol = (((lane & 7) ^ (lane >> 3)) * 8);

    f32x4 acc[4][4];
#pragma unroll
    for (int i = 0; i < 4; ++i)
#pragma unroll
        for (int j = 0; j < 4; ++j)
#pragma unroll
            for (int r = 0; r < 4; ++r) acc[i][j][r] = 0.f;

    for (int k0 = 0; k0 < K; k0 += 64) {
#pragma unroll
        for (int i = 0; i < 4; ++i) {
            int ra = srow + i * 8;
            int ga = m0 + ra; if (ga > M - 1) ga = M - 1;   // junk rows -> discarded C rows
            __builtin_amdgcn_global_load_lds(
                (const __attribute__((address_space(1))) void*)(A + (size_t)ga * lda + k0 + scol),
                (__attribute__((address_space(3))) void*)(As + wave * 2048 + i * 512),
                16, 0, 0);
            int gb = n0 + ra;
            __builtin_amdgcn_global_load_lds(
                (const __attribute__((address_space(1))) void*)(Bt + (size_t)gb * ldb + k0 + scol),
                (__attribute__((address_space(3))) void*)(Bs + wave * 2048 + i * 512),
                16, 0, 0);
        }
        __syncthreads();
#pragma unroll
        for (int kk = 0; kk < 2; ++kk) {
            const int coff = (((kk * 4 + (lane >> 4)) ^ (frow & 7)) << 3);
            bf16x8 af[4], bfr[4];
#pragma unroll
            for (int i = 0; i < 4; ++i) {
                af[i]  = *(const bf16x8*)(As + (wm + i * 16 + frow) * 64 + coff);
                bfr[i] = *(const bf16x8*)(Bs + (wn + i * 16 + frow) * 64 + coff);
            }
#pragma unroll
            for (int i = 0; i < 4; ++i)
#pragma unroll
                for (int j = 0; j < 4; ++j)
                    acc[i][j] = __builtin_amdgcn_mfma_f32_16x16x32_bf16(af[i], bfr[j], acc[i][j], 0, 0, 0);
        }
        __syncthreads();
    }

#pragma unroll
    for (int i = 0; i < 4; ++i) {
#pragma unroll
        for (int j = 0; j < 4; ++j) {
            int rbase = m0 + wm + i * 16 + (lane >> 4) * 4;
            int col   = n0 + wn + j * 16 + frow;
            if constexpr (BACT) {
                float bv = (float)bias[col];
#pragma unroll
                for (int r = 0; r < 4; ++r) {
                    int row = rbase + r;
                    if (row < M) {
                        float v = acc[i][j][r] + bv;
                        v = (v > 0.f) ? v : (expf(v) - 1.f);
                        C[(size_t)row * ldc + col] = (bf16)v;
                    }
                }
            } else {
#pragma unroll
                for (int r = 0; r < 4; ++r) {
                    int row = rbase + r;
                    if (row < M) C[(size_t)row * ldc + col] = (bf16)acc[i][j][r];
                }
            }
        }
    }
}

// ------------------------------------------------------------ prep kernels --
// x -> A2[n*KA + 256 + k] (padded to 64)
__global__ void k_padx(const void* __restrict__ x, bf16* __restrict__ A2,
                       const int* __restrict__ flags)
{
    int idx = blockIdx.x * 256 + threadIdx.x;
    if (idx >= N_NODES * 64) return;
    int isb = flags[1];
    int n = idx >> 6, k = idx & 63;
    A2[(size_t)n * KA + 256 + k] = (k < F_IN) ? (bf16)loadf(x, (long)n * F_IN + k, isb)
                                              : (bf16)0.f;
}

// ws[k][h] = sum_c W1[k, h*256+c]*a1s[h,c]; wd likewise; bsum = b1+bl1.
__global__ __launch_bounds__(256) void k_veca(const void* __restrict__ W1,
                                              const void* __restrict__ a1s,
                                              const void* __restrict__ a1d,
                                              const void* __restrict__ b1,
                                              const void* __restrict__ bl1,
                                              float* __restrict__ ws, float* __restrict__ wd,
                                              bf16* __restrict__ bsum,
                                              const int* __restrict__ flags)
{
    const int isb = flags[1];
    const int k = blockIdx.x;          // 0..63
    const int h = threadIdx.x >> 6;
    const int c0 = threadIdx.x & 63;
    float s = 0.f, d = 0.f;
    if (k < F_IN) {
        for (int c = c0; c < 256; c += 64) {
            float wv = loadf(W1, (long)k * D1 + h * 256 + c, isb);
            s += wv * loadf(a1s, h * 256 + c, isb);
            d += wv * loadf(a1d, h * 256 + c, isb);
        }
    }
#pragma unroll
    for (int off = 32; off; off >>= 1) {
        s += __shfl_xor(s, off);
        d += __shfl_xor(d, off);
    }
    if (c0 == 0) { ws[k * 4 + h] = s; wd[k * 4 + h] = d; }
    if (k < 4) {
        int j = k * 256 + threadIdx.x;
        bsum[j] = (bf16)(loadf(b1, j, isb) + loadf(bl1, j, isb));
    }
}

// fused layer-1 B^T [1024 x KA]: k'<256 blockdiag(W1), k'>=256 Wl1
__global__ void k_wfuse1(const void* __restrict__ W1, const void* __restrict__ Wl1,
                         bf16* __restrict__ Bt, const int* __restrict__ flags)
{
    int idx = blockIdx.x * 256 + threadIdx.x;
    if (idx >= D1 * KA) return;
    int isb = flags[1];
    int j = idx / KA;
    int kp = idx - j * KA;
    float v = 0.f;
    if (kp < 256) {
        int hp = kp >> 6, k = kp & 63;
        if ((j >> 8) == hp && k < F_IN) v = loadf(W1, (long)k * D1 + j, isb);
    } else {
        int k = kp - 256;
        if (k < F_IN) v = loadf(Wl1, (long)k * D1 + j, isb);
    }
    Bt[idx] = (bf16)v;
}

// Tiled transpose-concat: Bt[n][k] = [Wa | Wb | 0](k, n), K=1024 rows.
__global__ __launch_bounds__(256) void k_wcatT(const void* __restrict__ Wa,
                                               const void* __restrict__ Wb,
                                               bf16* __restrict__ Bt,
                                               int split, int da, int db,
                                               const int* __restrict__ flags)
{
    __shared__ bf16 T[64][65];
    const int isb = flags[1];
    const int k0 = blockIdx.x * 64;
    const int n0 = blockIdx.y * 64;
    const int r = threadIdx.x >> 6;    // 0..3
    const int c = threadIdx.x & 63;
    const int n = n0 + c;
#pragma unroll
    for (int kk = 0; kk < 16; ++kk) {
        int k = k0 + r + kk * 4;
        float v = 0.f;
        if (n < split)           v = loadf(Wa, (long)k * da + n, isb);
        else if (n < split + db) v = loadf(Wb, (long)k * db + (n - split), isb);
        T[r + kk * 4][c] = (bf16)v;
    }
    __syncthreads();
#pragma unroll
    for (int kk = 0; kk < 16; ++kk) {
        int nn = r + kk * 4;
        Bt[(size_t)(n0 + nn) * 1024 + k0 + c] = T[c][nn];
    }
}

struct P12 { const void* s[12]; };

__global__ void k_params(P12 ps, bf16* __restrict__ pool, const int* __restrict__ flags)
{
    const int off[13] = {PO_A1S, PO_A1D, PO_B1, PO_BL1, PO_A2S, PO_A2D, PO_B2,
                         PO_BL2, PO_A3S, PO_A3D, PO_B3, PO_BL3, PO_END};
    int idx = blockIdx.x * 256 + threadIdx.x;
    if (idx >= PO_END) return;
    int isb = flags[1];
    int seg = 0;
    while (idx >= off[seg + 1]) seg++;
    pool[idx] = (bf16)loadf(ps.s[seg], idx - off[seg], isb);
}

// ------------------------------------------------------------- CSR build ----
__global__ void k_count(const int* __restrict__ ei, int* __restrict__ cnt,
                        const int* __restrict__ flags)
{
    int e = blockIdx.x * 256 + threadIdx.x;
    if (e >= E2) return;
    int i64 = flags[0];
    int d = (e < N_EDGES) ? loadei(ei, (long)N_EDGES + e, i64) : (e - N_EDGES);
    d = clampi(d, 0, N_NODES - 1);
    atomicAdd(&cnt[d], 1);
}

__global__ __launch_bounds__(256) void k_scan(const int* __restrict__ cnt,
                                              int* __restrict__ rp, int* __restrict__ cur)
{
    __shared__ int ssum[256];
    int tid = threadIdx.x;
    const int chunk = (N_NODES + 255) / 256;
    int lo = tid * chunk;
    int hi = lo + chunk; if (hi > N_NODES) hi = N_NODES;
    int s = 0;
    for (int i = lo; i < hi; ++i) s += cnt[i];
    ssum[tid] = s;
    __syncthreads();
    if (tid == 0) {
        int run = 0;
        for (int i = 0; i < 256; ++i) { int t = ssum[i]; ssum[i] = run; run += t; }
        rp[N_NODES] = run;
    }
    __syncthreads();
    int run = ssum[tid];
    for (int i = lo; i < hi; ++i) {
        rp[i] = run; cur[i] = run;
        run += cnt[i];
    }
}

__global__ void k_fill(const int* __restrict__ ei, int* __restrict__ cur,
                       int* __restrict__ ss, const int* __restrict__ flags)
{
    int e = blockIdx.x * 256 + threadIdx.x;
    if (e >= E2) return;
    int i64 = flags[0];
    int s, d;
    if (e < N_EDGES) {
        s = loadei(ei, e, i64);
        d = loadei(ei, (long)N_EDGES + e, i64);
    } else {
        s = e - N_EDGES; d = s;
    }
    s = clampi(s, 0, N_NODES - 1);
    d = clampi(d, 0, N_NODES - 1);
    int pos = atomicAdd(&cur[d], 1);
    if (pos >= 0 && pos < E2) ss[pos] = s;
}

// ----------------------------------------------------- attention kernels ----
// layer-1 logits: es[n,h] = sum_k x[n,k]*ws[k,h] (wave per node)
__global__ __launch_bounds__(256) void k_logits1(const bf16* __restrict__ A2,
                                                 const float* __restrict__ ws,
                                                 const float* __restrict__ wd,
                                                 float* __restrict__ es, float* __restrict__ ed)
{
    const int wave = threadIdx.x >> 6;
    const int lane = threadIdx.x & 63;
    const int n = blockIdx.x * 4 + wave;
    if (n >= N_NODES) return;
    float xv = (float)A2[(size_t)n * KA + 256 + lane];
    f32x4 wsv = *(const f32x4*)(ws + lane * 4);
    f32x4 wdv = *(const f32x4*)(wd + lane * 4);
    float s[4], d[4];
#pragma unroll
    for (int h = 0; h < 4; ++h) { s[h] = xv * wsv[h]; d[h] = xv * wdv[h]; }
#pragma unroll
    for (int off = 32; off; off >>= 1)
#pragma unroll
        for (int h = 0; h < 4; ++h) {
            s[h] += __shfl_xor(s[h], off);
            d[h] += __shfl_xor(d[h], off);
        }
    if (lane == 0) {
#pragma unroll
        for (int h = 0; h < 4; ++h) { es[n * 4 + h] = s[h]; ed[n * 4 + h] = d[h]; }
    }
}

// layer-1 aggregate: aggx[n,h,k] = sum_e alpha[e,h] x[src_e,k] (block per node)
__global__ __launch_bounds__(256) void k_aggx(bf16* __restrict__ A2,
                                              const float* __restrict__ es,
                                              const float* __restrict__ ed,
                                              const int* __restrict__ rp,
                                              const int* __restrict__ ss)
{
    __shared__ float smx[4], sinv[4], sed[4];
    __shared__ float sal[64 * 4];
    __shared__ int   ssrc[64];

    const int n   = blockIdx.x;
    const int tid = threadIdx.x;
    int r0 = clampi(rp[n], 0, E2);
    int r1 = clampi(rp[n + 1], r0, E2);
    const int deg = r1 - r0;

    const int sw = tid >> 5, ln = tid & 31;
    if (sw < 4) {
        int h = sw;
        float edn = ed[n * 4 + h];
        float mx = -1e30f;
        for (int e = ln; e < deg; e += 32) {
            int s = clampi(ss[r0 + e], 0, N_NODES - 1);
            float w = es[s * 4 + h] + edn;
            w = (w > 0.f) ? w : 0.2f * w;
            mx = fmaxf(mx, w);
        }
#pragma unroll
        for (int off = 16; off; off >>= 1) mx = fmaxf(mx, __shfl_xor(mx, off, 32));
        float sm = 0.f;
        for (int e = ln; e < deg; e += 32) {
            int s = clampi(ss[r0 + e], 0, N_NODES - 1);
            float w = es[s * 4 + h] + edn;
            w = (w > 0.f) ? w : 0.2f * w;
            sm += expf(w - mx);
        }
#pragma unroll
        for (int off = 16; off; off >>= 1) sm += __shfl_xor(sm, off, 32);
        if (ln == 0) { smx[h] = mx; sinv[h] = 1.f / fmaxf(sm, 1e-16f); sed[h] = edn; }
    }
    __syncthreads();

    const int k  = tid & 63;
    const int hh = tid >> 6;
    float acc = 0.f;

    for (int e0 = 0; e0 < deg; e0 += 64) {
        int ce = min(64, deg - e0);
        __syncthreads();
        if (tid < ce * 4) {
            int e = tid >> 2, h = tid & 3;
            int s = clampi(ss[r0 + e0 + e], 0, N_NODES - 1);
            float w = es[s * 4 + h] + sed[h];
            w = (w > 0.f) ? w : 0.2f * w;
            sal[e * 4 + h] = expf(w - smx[h]) * sinv[h];
            if (h == 0) ssrc[e] = s;
        }
        __syncthreads();
        for (int e = 0; e < ce; ++e) {
            int s = ssrc[e];
            float xv = (float)A2[(size_t)s * KA + 256 + k];
            acc += sal[e * 4 + hh] * xv;
        }
    }
    A2[(size_t)n * KA + hh * 64 + k] = (bf16)acc;
}

// layers 2/3 logits on h (wave per node)
template <int H, int C>
__global__ __launch_bounds__(256) void k_logits(const bf16* __restrict__ G,
                                                const bf16* __restrict__ as_,
                                                const bf16* __restrict__ ad_,
                                                float* __restrict__ es, float* __restrict__ ed)
{
    const int wave = threadIdx.x >> 6;
    const int lane = threadIdx.x & 63;
    const int n = blockIdx.x * 4 + wave;
    if (n >= N_NODES) return;

#pragma unroll
    for (int h = 0; h < H; ++h) {
        float s = 0.f, d = 0.f;
        if constexpr (C == 256) {
            bf16x4 g  = *(const bf16x4*)(G + (size_t)n * SG + h * 256 + lane * 4);
            bf16x4 av = *(const bf16x4*)(as_ + h * 256 + lane * 4);
            bf16x4 dv = *(const bf16x4*)(ad_ + h * 256 + lane * 4);
#pragma unroll
            for (int j = 0; j < 4; ++j) {
                float gv = (float)g[j];
                s += gv * (float)av[j];
                d += gv * (float)dv[j];
            }
        } else {
            for (int c = lane; c < C; c += 64) {
                float hv = (float)G[(size_t)n * SG + h * C + c];
                s += hv * (float)as_[h * C + c];
                d += hv * (float)ad_[h * C + c];
            }
        }
#pragma unroll
        for (int off = 32; off; off >>= 1) {
            s += __shfl_xor(s, off);
            d += __shfl_xor(d, off);
        }
        if (lane == 0) { es[n * H + h] = s; ed[n * H + h] = d; }
    }
}

// Fused per-dst-node softmax + gather-aggregate + bias + skip (+mean/ELU).
// Phase 2: 4-wide edge grouping (measured optimum: VGPR 20, occ ~80%).
template <int H, int C, bool MEAN, bool ELU, bool EXTOUT>
__global__ __launch_bounds__(256) void k_agg(const bf16* __restrict__ G,
                                             const bf16* __restrict__ S,
                                             const float* __restrict__ es,
                                             const float* __restrict__ ed,
                                             const int* __restrict__ rp,
                                             const int* __restrict__ ss,
                                             const bf16* __restrict__ bgat,
                                             const bf16* __restrict__ bskip,
                                             void* __restrict__ out, int sout,
                                             const int* __restrict__ flags)
{
    constexpr int D  = H * C;
    constexpr int NV = (D + 3) / 4;
    constexpr int CH = 256;
    __shared__ float smx[H], sinv[H], sed[H];
    __shared__ float sal[CH * H];
    __shared__ int   ssrc[CH];

    const int n   = blockIdx.x;
    const int tid = threadIdx.x;
    int r0 = clampi(rp[n], 0, E2);
    int r1 = clampi(rp[n + 1], r0, E2);
    const int deg = r1 - r0;

    const int sw = tid >> 5, ln = tid & 31;
    for (int h = sw; h < H; h += 8) {
        float edn = ed[n * H + h];
        float mx = -1e30f;
        for (int e = ln; e < deg; e += 32) {
            int s = clampi(ss[r0 + e], 0, N_NODES - 1);
            float w = es[s * H + h] + edn;
            w = (w > 0.f) ? w : 0.2f * w;
            mx = fmaxf(mx, w);
        }
#pragma unroll
        for (int off = 16; off; off >>= 1) mx = fmaxf(mx, __shfl_xor(mx, off, 32));
        float sm = 0.f;
        for (int e = ln; e < deg; e += 32) {
            int s = clampi(ss[r0 + e], 0, N_NODES - 1);
            float w = es[s * H + h] + edn;
            w = (w > 0.f) ? w : 0.2f * w;
            sm += expf(w - mx);
        }
#pragma unroll
        for (int off = 16; off; off >>= 1) sm += __shfl_xor(sm, off, 32);
        if (ln == 0) { smx[h] = mx; sinv[h] = 1.f / fmaxf(sm, 1e-16f); sed[h] = edn; }
    }
    __syncthreads();

    const int c0 = tid * 4;
    const int hA = (c0 < D) ? (c0 / C) : 0;
    const int hB = (c0 + 3 < D) ? ((c0 + 3) / C) : hA;
    int hj1 = ((c0 + 1 < D) ? ((c0 + 1) / C) : hA) == hA;
    int hj2 = ((c0 + 2 < D) ? ((c0 + 2) / C) : hA) == hA;
    const bool active = (tid < NV);

    float acc[4] = {0.f, 0.f, 0.f, 0.f};

    for (int e0 = 0; e0 < deg; e0 += CH) {
        int ce = min(CH, deg - e0);
        __syncthreads();
        for (int t = tid; t < ce * H; t += 256) {
            int e = t / H, h = t - e * H;
            int s = clampi(ss[r0 + e0 + e], 0, N_NODES - 1);
            float w = es[s * H + h] + sed[h];
            w = (w > 0.f) ? w : 0.2f * w;
            sal[e * H + h] = expf(w - smx[h]) * sinv[h];
            if (h == 0) ssrc[e] = s;
        }
        __syncthreads();
        if (active) {
            for (int eb = 0; eb < ce; eb += 4) {
                int idx[4]; float zm[4];
#pragma unroll
                for (int p = 0; p < 4; ++p) {
                    int e = eb + p;
                    idx[p] = (e < ce) ? e : eb;
                    zm[p]  = (e < ce) ? 1.f : 0.f;
                }
                int sg[4];
#pragma unroll
                for (int p = 0; p < 4; ++p) sg[p] = ssrc[idx[p]];
                bf16x4 g[4];
#pragma unroll
                for (int p = 0; p < 4; ++p)
                    g[p] = *(const bf16x4*)(G + (size_t)sg[p] * SG + c0);
                if constexpr (C % 4 == 0) {
                    float a[4];
#pragma unroll
                    for (int p = 0; p < 4; ++p) a[p] = sal[idx[p] * H + hA] * zm[p];
#pragma unroll
                    for (int p = 0; p < 4; ++p)
#pragma unroll
                        for (int j = 0; j < 4; ++j)
                            acc[j] += a[p] * (float)g[p][j];
                } else {
                    float aL[4], aH[4];
#pragma unroll
                    for (int p = 0; p < 4; ++p) {
                        aL[p] = sal[idx[p] * H + hA] * zm[p];
                        aH[p] = sal[idx[p] * H + hB] * zm[p];
                    }
#pragma unroll
                    for (int p = 0; p < 4; ++p) {
                        acc[0] += aL[p] * (float)g[p][0];
                        acc[1] += (hj1 ? aL[p] : aH[p]) * (float)g[p][1];
                        acc[2] += (hj2 ? aL[p] : aH[p]) * (float)g[p][2];
                        acc[3] += aH[p] * (float)g[p][3];
                    }
                }
            }
        }
    }

    const int outbf = EXTOUT ? flags[1] : 1;

    if constexpr (!MEAN) {
        if (active) {
            bf16x4 bg = *(const bf16x4*)(bgat + c0);
            bf16x4 sk = *(const bf16x4*)(S + (size_t)n * SG + c0);
            bf16x4 bs = *(const bf16x4*)(bskip + c0);
            bf16x4 ov;
#pragma unroll
            for (int j = 0; j < 4; ++j) {
                float v = acc[j] + (float)bg[j] + (float)sk[j] + (float)bs[j];
                if (ELU) v = (v > 0.f) ? v : (expf(v) - 1.f);
                ov[j] = (bf16)v;
            }
            *(bf16x4*)((bf16*)out + (size_t)n * sout + c0) = ov;
        }
    } else {
        __shared__ float sagg[D];
        if (active) {
#pragma unroll
            for (int j = 0; j < 4; ++j) {
                int c = c0 + j;
                if (c < D) sagg[c] = acc[j];
            }
        }
        __syncthreads();
        for (int c = tid; c < C; c += 256) {
            float v = 0.f;
#pragma unroll
            for (int h = 0; h < H; ++h) v += sagg[h * C + c];
            v *= (1.f / H);
            v += (float)bgat[c] + (float)S[(size_t)n * SG + c] + (float)bskip[c];
            if (outbf) ((bf16*)out)[(size_t)n * sout + c] = (bf16)v;
            else       ((float*)out)[(size_t)n * sout + c] = v;
        }
    }
}

// ----------------------------------------------------------------- launch ---
extern "C" void kernel_launch(void* const* d_in, const int* in_sizes, int n_in,
                              void* d_out, int out_size, void* d_ws, size_t ws_size,
                              hipStream_t stream)
{
    const void* x   = d_in[0];
    const int*  ei  = (const int*)d_in[1];
    const void* W1  = d_in[2];
    const void* Wl1 = d_in[6];
    const void* W2  = d_in[8];
    const void* Wl2 = d_in[12];
    const void* W3  = d_in[14];
    const void* Wl3 = d_in[18];

    P12 ps;
    ps.s[0] = d_in[3];  ps.s[1] = d_in[4];  ps.s[2] = d_in[5];  ps.s[3] = d_in[7];
    ps.s[4] = d_in[9];  ps.s[5] = d_in[10]; ps.s[6] = d_in[11]; ps.s[7] = d_in[13];
    ps.s[8] = d_in[15]; ps.s[9] = d_in[16]; ps.s[10] = d_in[17]; ps.s[11] = d_in[19];

    char* w = (char*)d_ws;
    auto alloc = [&](size_t bytes) {
        char* p = w;
        w += (bytes + 255) & ~(size_t)255;
        return p;
    };
    int*   flags = (int*)alloc(64);
    int*   cnt   = (int*)alloc((size_t)N_NODES * 4);
    int*   rp    = (int*)alloc((size_t)(N_NODES + 1) * 4);
    int*   cur   = (int*)alloc((size_t)N_NODES * 4);
    int*   ss    = (int*)alloc((size_t)E2 * 4);
    float* es    = (float*)alloc((size_t)N_NODES * 6 * 4);
    float* ed    = (float*)alloc((size_t)N_NODES * 6 * 4);
    bf16*  pool  = (bf16*)alloc((size_t)PO_END * 2);
    float* ws1   = (float*)alloc((size_t)64 * 4 * 4);
    float* wd1   = (float*)alloc((size_t)64 * 4 * 4);
    bf16*  bsum  = (bf16*)alloc((size_t)D1 * 2);
    bf16*  Bt    = (bf16*)alloc((size_t)NP12 * 1024 * 2);
    bf16*  X     = (bf16*)alloc((size_t)N_NODES * D1 * 2);   // x1/x2
    bf16*  WS    = (bf16*)alloc((size_t)N_NODES * SG * 2);   // GEMM out [gat|skip]
    bf16*  A2    = WS;   // layer-1 A'' [N x KA] aliases WS (dead during layer 1)

    k_detect<<<1, 256, 0, stream>>>(ei, (const unsigned short*)x, flags);

    hipMemsetAsync(cnt, 0, N_NODES * 4, stream);
    k_count<<<(E2 + 255) / 256, 256, 0, stream>>>(ei, cnt, flags);
    k_scan<<<1, 256, 0, stream>>>(cnt, rp, cur);
    k_fill<<<(E2 + 255) / 256, 256, 0, stream>>>(ei, cur, ss, flags);

    k_params<<<(PO_END + 255) / 256, 256, 0, stream>>>(ps, pool, flags);

    const dim3 blk(256);
    const int MT = (N_NODES + 127) / 128;   // 157

    // ---- layer 1 (restructured): aggregate x, then fused GEMM K=320
    k_veca<<<64, 256, 0, stream>>>(W1, ps.s[0], ps.s[1], ps.s[2], ps.s[3],
                                   ws1, wd1, bsum, flags);
    k_padx<<<(N_NODES * 64 + 255) / 256, 256, 0, stream>>>(x, A2, flags);
    k_wfuse1<<<(D1 * KA + 255) / 256, 256, 0, stream>>>(W1, Wl1, Bt, flags);
    k_logits1<<<N_NODES / 4, 256, 0, stream>>>(A2, ws1, wd1, es, ed);
    k_aggx<<<N_NODES, 256, 0, stream>>>(A2, es, ed, rp, ss);
    k_gemm<true><<<MT * (D1 / 128), blk, 0, stream>>>(A2, Bt, X, N_NODES, KA, KA, KA, D1,
                                                      MT, D1 / 128, bsum);   // x1 = ELU(...)

    // ---- layer 2: K=1024, out 2048 = [GAT 1024 | skip 1024]
    k_wcatT<<<dim3(16, NP12 / 64), blk, 0, stream>>>(W2, Wl2, Bt, 1024, 1024, 1024, flags);
    k_gemm<false><<<MT * (NP12 / 128), blk, 0, stream>>>(X, Bt, WS, N_NODES, 1024, 1024, 1024, SG,
                                                         MT, NP12 / 128, nullptr);
    k_logits<4, 256><<<N_NODES / 4, 256, 0, stream>>>(WS, pool + PO_A2S, pool + PO_A2D, es, ed);
    k_agg<4, 256, false, true, false><<<N_NODES, 256, 0, stream>>>(
        WS, WS + D1, es, ed, rp, ss, pool + PO_B2, pool + PO_BL2, X, D1, flags);

    // ---- layer 3: K=1024, out 896 = [GAT 726 | skip 121 | pad]
    k_wcatT<<<dim3(16, NP3 / 64), blk, 0, stream>>>(W3, Wl3, Bt, 726, 726, 121, flags);
    k_gemm<false><<<MT * (NP3 / 128), blk, 0, stream>>>(X, Bt, WS, N_NODES, 1024, 1024, 1024, SG,
                                                        MT, NP3 / 128, nullptr);
    k_logits<6, 121><<<N_NODES / 4, 256, 0, stream>>>(WS, pool + PO_A3S, pool + PO_A3D, es, ed);
    k_agg<6, 121, true, false, true><<<N_NODES, 256, 0, stream>>>(
        WS, WS + 726, es, ed, rp, ss, pool + PO_B3, pool + PO_BL3, d_out, 121, flags);
}

// Round 14
// 656.815 us; speedup vs baseline: 1.0587x; 1.0080x over previous
//
#include <hip/hip_runtime.h>
#include <hip/hip_bf16.h>
#include <math.h>

typedef __bf16 bf16;
typedef __attribute__((ext_vector_type(4))) __bf16 bf16x4;
typedef __attribute__((ext_vector_type(8))) __bf16 bf16x8;
typedef __attribute__((ext_vector_type(4))) float f32x4;

#define N_NODES 20000
#define N_EDGES 320000
#define E2 (N_EDGES + N_NODES)   // 340000 edges incl self-loops
#define F_IN 50
#define D1 1024                  // H1*C1
#define NP12 2048                // padded GEMM out-cols, layer 2 ([W|Wl])
#define NP3 896                  // padded GEMM out-cols, layer 3 (726+121=847 -> 896)
#define SG 2048                  // row stride of GEMM output buffer
#define KA 320                   // layer-1 fused K: 4*64 aggx + 64 x

// params pool element offsets (bf16 pool)
#define PO_A1S 0
#define PO_A1D 1024
#define PO_B1  2048
#define PO_BL1 3072
#define PO_A2S 4096
#define PO_A2D 5120
#define PO_B2  6144
#define PO_BL2 7168
#define PO_A3S 8192
#define PO_A3D 8918
#define PO_B3  9644
#define PO_BL3 9765
#define PO_END 9886

__device__ __forceinline__ int clampi(int v, int lo, int hi)
{
    return v < lo ? lo : (v > hi ? hi : v);
}

__device__ __forceinline__ float loadf(const void* p, long idx, int isb)
{
    return isb ? (float)((const bf16*)p)[idx] : ((const float*)p)[idx];
}

__device__ __forceinline__ int loadei(const int* ei, long idx, int i64)
{
    return i64 ? ei[2 * idx] : ei[idx];
}

// --------------------------------------------------------------- detect -----
// grid 79 blocks: block 0 detects dtypes; all blocks zero cnt (kills memset).
__global__ void k_detect(const int* __restrict__ ei,
                         const unsigned short* __restrict__ xw,
                         int* __restrict__ flags, int* __restrict__ cnt)
{
    int gi = blockIdx.x * 256 + threadIdx.x;
    if (gi < N_NODES) cnt[gi] = 0;
    if (blockIdx.x != 0) return;

    __shared__ int bad64, cexp;
    int t = threadIdx.x;
    if (t == 0) { bad64 = 0; cexp = 0; }
    __syncthreads();
    if (t < 128) {
        if (ei[2 * t + 1] != 0) atomicAdd(&bad64, 1);
    } else {
        int i = t - 128;
        int e = (xw[2 * i] >> 7) & 0xFF;
        if (e >= 100 && e <= 140) atomicAdd(&cexp, 1);
    }
    __syncthreads();
    if (t == 0) {
        flags[0] = (bad64 == 0) ? 1 : 0;
        flags[1] = (cexp >= 64) ? 1 : 0;
    }
}

// ---------------------------------------------------------------- GEMM ------
// m97-style 128x128 tile, BK=64, global_load_lds width-16, XCD swizzle,
// XOR k-chunk LDS swizzle. BACT (compile-time): fused bias+ELU epilogue.
template <bool BACT>
__global__ __launch_bounds__(256) void k_gemm(const bf16* __restrict__ A,
                                              const bf16* __restrict__ Bt,
                                              bf16* __restrict__ C,
                                              int M, int K, int lda, int ldb, int ldc,
                                              int mtiles, int ntiles,
                                              const bf16* __restrict__ bias)
{
    __shared__ bf16 As[128 * 64];
    __shared__ bf16 Bs[128 * 64];

    int id = blockIdx.x;
    int gfull = mtiles >> 3;
    int base  = gfull * 8 * ntiles;
    int x, y;
    if (id < base) {
        int gsz = 8 * ntiles;
        int g = id / gsz;
        int r = id - g * gsz;
        x = g * 8 + (r & 7);
        y = r >> 3;
    } else {
        int rem = mtiles - (gfull << 3);
        int r = id - base;
        x = (gfull << 3) + r % rem;
        y = r / rem;
    }
    const int m0 = x * 128;
    const int n0 = y * 128;

    const int tid  = threadIdx.x;
    const int wave = tid >> 6;
    const int lane = tid & 63;
    const int wm   = (wave >> 1) * 64;
    const int wn   = (wave & 1) * 64;
    const int frow  = lane & 15;

    const int srow = wave * 32 + (lane >> 3);
    const int scol = (((lane & 7) ^ (lane >> 3)) * 8);

    f32x4 acc[4][4];
#pragma unroll
    for (int i = 0; i < 4; ++i)
#pragma unroll
        for (int j = 0; j < 4; ++j)
#pragma unroll
            for (int r = 0; r < 4; ++r) acc[i][j][r] = 0.f;

    for (int k0 = 0; k0 < K; k0 += 64) {
#pragma unroll
        for (int i = 0; i < 4; ++i) {
            int ra = srow + i * 8;
            int ga = m0 + ra; if (ga > M - 1) ga = M - 1;   // junk rows -> discarded C rows
            __builtin_amdgcn_global_load_lds(
                (const __attribute__((address_space(1))) void*)(A + (size_t)ga * lda + k0 + scol),
                (__attribute__((address_space(3))) void*)(As + wave * 2048 + i * 512),
                16, 0, 0);
            int gb = n0 + ra;
            __builtin_amdgcn_global_load_lds(
                (const __attribute__((address_space(1))) void*)(Bt + (size_t)gb * ldb + k0 + scol),
                (__attribute__((address_space(3))) void*)(Bs + wave * 2048 + i * 512),
                16, 0, 0);
        }
        __syncthreads();
#pragma unroll
        for (int kk = 0; kk < 2; ++kk) {
            const int coff = (((kk * 4 + (lane >> 4)) ^ (frow & 7)) << 3);
            bf16x8 af[4], bfr[4];
#pragma unroll
            for (int i = 0; i < 4; ++i) {
                af[i]  = *(const bf16x8*)(As + (wm + i * 16 + frow) * 64 + coff);
                bfr[i] = *(const bf16x8*)(Bs + (wn + i * 16 + frow) * 64 + coff);
            }
#pragma unroll
            for (int i = 0; i < 4; ++i)
#pragma unroll
                for (int j = 0; j < 4; ++j)
                    acc[i][j] = __builtin_amdgcn_mfma_f32_16x16x32_bf16(af[i], bfr[j], acc[i][j], 0, 0, 0);
        }
        __syncthreads();
    }

#pragma unroll
    for (int i = 0; i < 4; ++i) {
#pragma unroll
        for (int j = 0; j < 4; ++j) {
            int rbase = m0 + wm + i * 16 + (lane >> 4) * 4;
            int col   = n0 + wn + j * 16 + frow;
            if constexpr (BACT) {
                float bv = (float)bias[col];
#pragma unroll
                for (int r = 0; r < 4; ++r) {
                    int row = rbase + r;
                    if (row < M) {
                        float v = acc[i][j][r] + bv;
                        v = (v > 0.f) ? v : (expf(v) - 1.f);
                        C[(size_t)row * ldc + col] = (bf16)v;
                    }
                }
            } else {
#pragma unroll
                for (int r = 0; r < 4; ++r) {
                    int row = rbase + r;
                    if (row < M) C[(size_t)row * ldc + col] = (bf16)acc[i][j][r];
                }
            }
        }
    }
}

// --------------------------------------------------------- mega-prep --------
struct P12 { const void* s[12]; };

__device__ void d_params(int b, P12 ps, bf16* __restrict__ pool, int isb)
{
    const int off[13] = {PO_A1S, PO_A1D, PO_B1, PO_BL1, PO_A2S, PO_A2D, PO_B2,
                         PO_BL2, PO_A3S, PO_A3D, PO_B3, PO_BL3, PO_END};
    int idx = b * 256 + threadIdx.x;
    if (idx >= PO_END) return;
    int seg = 0;
    while (idx >= off[seg + 1]) seg++;
    pool[idx] = (bf16)loadf(ps.s[seg], idx - off[seg], isb);
}

__device__ void d_veca(int k, const void* __restrict__ W1,
                       const void* __restrict__ a1s, const void* __restrict__ a1d,
                       const void* __restrict__ b1, const void* __restrict__ bl1,
                       float* __restrict__ ws, float* __restrict__ wd,
                       bf16* __restrict__ bsum, int isb)
{
    const int h = threadIdx.x >> 6;
    const int c0 = threadIdx.x & 63;
    float s = 0.f, d = 0.f;
    if (k < F_IN) {
        for (int c = c0; c < 256; c += 64) {
            float wv = loadf(W1, (long)k * D1 + h * 256 + c, isb);
            s += wv * loadf(a1s, h * 256 + c, isb);
            d += wv * loadf(a1d, h * 256 + c, isb);
        }
    }
#pragma unroll
    for (int off = 32; off; off >>= 1) {
        s += __shfl_xor(s, off);
        d += __shfl_xor(d, off);
    }
    if (c0 == 0) { ws[k * 4 + h] = s; wd[k * 4 + h] = d; }
    if (k < 4) {
        int j = k * 256 + threadIdx.x;
        bsum[j] = (bf16)(loadf(b1, j, isb) + loadf(bl1, j, isb));
    }
}

__device__ void d_padx(int b, const void* __restrict__ x, bf16* __restrict__ A2, int isb)
{
    int idx = b * 256 + threadIdx.x;
    if (idx >= N_NODES * 64) return;
    int n = idx >> 6, k = idx & 63;
    A2[(size_t)n * KA + 256 + k] = (k < F_IN) ? (bf16)loadf(x, (long)n * F_IN + k, isb)
                                              : (bf16)0.f;
}

__device__ void d_wfuse1(int b, const void* __restrict__ W1,
                         const void* __restrict__ Wl1, bf16* __restrict__ Bt, int isb)
{
    int idx = b * 256 + threadIdx.x;
    if (idx >= D1 * KA) return;
    int j = idx / KA;
    int kp = idx - j * KA;
    float v = 0.f;
    if (kp < 256) {
        int hp = kp >> 6, k = kp & 63;
        if ((j >> 8) == hp && k < F_IN) v = loadf(W1, (long)k * D1 + j, isb);
    } else {
        int k = kp - 256;
        if (k < F_IN) v = loadf(Wl1, (long)k * D1 + j, isb);
    }
    Bt[idx] = (bf16)v;
}

#define PB_PARAMS 39
#define PB_VECA   64
#define PB_PADX   5000
#define PB_WFUSE  1280
#define PB_TOTAL  (PB_PARAMS + PB_VECA + PB_PADX + PB_WFUSE)

__global__ __launch_bounds__(256) void k_prep(P12 ps, bf16* __restrict__ pool,
                                              const void* __restrict__ x,
                                              const void* __restrict__ W1,
                                              const void* __restrict__ Wl1,
                                              float* __restrict__ ws, float* __restrict__ wd,
                                              bf16* __restrict__ bsum,
                                              bf16* __restrict__ A2,
                                              bf16* __restrict__ BtL1,
                                              const int* __restrict__ flags)
{
    const int isb = flags[1];
    int b = blockIdx.x;
    if (b < PB_PARAMS) {
        d_params(b, ps, pool, isb);
    } else if (b < PB_PARAMS + PB_VECA) {
        d_veca(b - PB_PARAMS, W1, ps.s[0], ps.s[1], ps.s[2], ps.s[3], ws, wd, bsum, isb);
    } else if (b < PB_PARAMS + PB_VECA + PB_PADX) {
        d_padx(b - PB_PARAMS - PB_VECA, x, A2, isb);
    } else {
        d_wfuse1(b - PB_PARAMS - PB_VECA - PB_PADX, W1, Wl1, BtL1, isb);
    }
}

// Tiled transpose-concat for BOTH layers 2 & 3 in one launch.
// y < 32: Bt2 <- [W2|Wl2]; else: Bt3 <- [W3|Wl3|0].
__global__ __launch_bounds__(256) void k_wcat2(const void* __restrict__ W2,
                                               const void* __restrict__ Wl2,
                                               const void* __restrict__ W3,
                                               const void* __restrict__ Wl3,
                                               bf16* __restrict__ Bt2,
                                               bf16* __restrict__ Bt3,
                                               const int* __restrict__ flags)
{
    __shared__ bf16 T[64][65];
    const int isb = flags[1];
    const int k0 = blockIdx.x * 64;
    int yy = blockIdx.y;
    const void* Wa; const void* Wb; bf16* Bt; int split, da, db, n0;
    if (yy < 32) { Wa = W2; Wb = Wl2; Bt = Bt2; split = 1024; da = 1024; db = 1024; n0 = yy * 64; }
    else         { Wa = W3; Wb = Wl3; Bt = Bt3; split = 726;  da = 726;  db = 121;  n0 = (yy - 32) * 64; }
    const int r = threadIdx.x >> 6;    // 0..3
    const int c = threadIdx.x & 63;
    const int n = n0 + c;
#pragma unroll
    for (int kk = 0; kk < 16; ++kk) {
        int k = k0 + r + kk * 4;
        float v = 0.f;
        if (n < split)           v = loadf(Wa, (long)k * da + n, isb);
        else if (n < split + db) v = loadf(Wb, (long)k * db + (n - split), isb);
        T[r + kk * 4][c] = (bf16)v;
    }
    __syncthreads();
#pragma unroll
    for (int kk = 0; kk < 16; ++kk) {
        int nn = r + kk * 4;
        Bt[(size_t)(n0 + nn) * 1024 + k0 + c] = T[c][nn];
    }
}

// ------------------------------------------------------------- CSR build ----
__global__ void k_count(const int* __restrict__ ei, int* __restrict__ cnt,
                        const int* __restrict__ flags)
{
    int e = blockIdx.x * 256 + threadIdx.x;
    if (e >= E2) return;
    int i64 = flags[0];
    int d = (e < N_EDGES) ? loadei(ei, (long)N_EDGES + e, i64) : (e - N_EDGES);
    d = clampi(d, 0, N_NODES - 1);
    atomicAdd(&cnt[d], 1);
}

__global__ __launch_bounds__(256) void k_scan(const int* __restrict__ cnt,
                                              int* __restrict__ rp, int* __restrict__ cur)
{
    __shared__ int ssum[256];
    int tid = threadIdx.x;
    const int chunk = (N_NODES + 255) / 256;
    int lo = tid * chunk;
    int hi = lo + chunk; if (hi > N_NODES) hi = N_NODES;
    int s = 0;
    for (int i = lo; i < hi; ++i) s += cnt[i];
    ssum[tid] = s;
    __syncthreads();
    if (tid == 0) {
        int run = 0;
        for (int i = 0; i < 256; ++i) { int t = ssum[i]; ssum[i] = run; run += t; }
        rp[N_NODES] = run;
    }
    __syncthreads();
    int run = ssum[tid];
    for (int i = lo; i < hi; ++i) {
        rp[i] = run; cur[i] = run;
        run += cnt[i];
    }
}

__global__ void k_fill(const int* __restrict__ ei, int* __restrict__ cur,
                       int* __restrict__ ss, const int* __restrict__ flags)
{
    int e = blockIdx.x * 256 + threadIdx.x;
    if (e >= E2) return;
    int i64 = flags[0];
    int s, d;
    if (e < N_EDGES) {
        s = loadei(ei, e, i64);
        d = loadei(ei, (long)N_EDGES + e, i64);
    } else {
        s = e - N_EDGES; d = s;
    }
    s = clampi(s, 0, N_NODES - 1);
    d = clampi(d, 0, N_NODES - 1);
    int pos = atomicAdd(&cur[d], 1);
    if (pos >= 0 && pos < E2) ss[pos] = s;
}

// ----------------------------------------------------- attention kernels ----
// layer-1 logits: es[n,h] = sum_k x[n,k]*ws[k,h] (wave per node)
__global__ __launch_bounds__(256) void k_logits1(const bf16* __restrict__ A2,
                                                 const float* __restrict__ ws,
                                                 const float* __restrict__ wd,
                                                 float* __restrict__ es, float* __restrict__ ed)
{
    const int wave = threadIdx.x >> 6;
    const int lane = threadIdx.x & 63;
    const int n = blockIdx.x * 4 + wave;
    if (n >= N_NODES) return;
    float xv = (float)A2[(size_t)n * KA + 256 + lane];
    f32x4 wsv = *(const f32x4*)(ws + lane * 4);
    f32x4 wdv = *(const f32x4*)(wd + lane * 4);
    float s[4], d[4];
#pragma unroll
    for (int h = 0; h < 4; ++h) { s[h] = xv * wsv[h]; d[h] = xv * wdv[h]; }
#pragma unroll
    for (int off = 32; off; off >>= 1)
#pragma unroll
        for (int h = 0; h < 4; ++h) {
            s[h] += __shfl_xor(s[h], off);
            d[h] += __shfl_xor(d[h], off);
        }
    if (lane == 0) {
#pragma unroll
        for (int h = 0; h < 4; ++h) { es[n * 4 + h] = s[h]; ed[n * 4 + h] = d[h]; }
    }
}

// layer-1 aggregate: aggx[n,h,k] = sum_e alpha[e,h] x[src_e,k] (block per node)
__global__ __launch_bounds__(256) void k_aggx(bf16* __restrict__ A2,
                                              const float* __restrict__ es,
                                              const float* __restrict__ ed,
                                              const int* __restrict__ rp,
                                              const int* __restrict__ ss)
{
    __shared__ float smx[4], sinv[4], sed[4];
    __shared__ float sal[64 * 4];
    __shared__ int   ssrc[64];

    const int n   = blockIdx.x;
    const int tid = threadIdx.x;
    int r0 = clampi(rp[n], 0, E2);
    int r1 = clampi(rp[n + 1], r0, E2);
    const int deg = r1 - r0;

    const int sw = tid >> 5, ln = tid & 31;
    if (sw < 4) {
        int h = sw;
        float edn = ed[n * 4 + h];
        float mx = -1e30f;
        for (int e = ln; e < deg; e += 32) {
            int s = clampi(ss[r0 + e], 0, N_NODES - 1);
            float w = es[s * 4 + h] + edn;
            w = (w > 0.f) ? w : 0.2f * w;
            mx = fmaxf(mx, w);
        }
#pragma unroll
        for (int off = 16; off; off >>= 1) mx = fmaxf(mx, __shfl_xor(mx, off, 32));
        float sm = 0.f;
        for (int e = ln; e < deg; e += 32) {
            int s = clampi(ss[r0 + e], 0, N_NODES - 1);
            float w = es[s * 4 + h] + edn;
            w = (w > 0.f) ? w : 0.2f * w;
            sm += expf(w - mx);
        }
#pragma unroll
        for (int off = 16; off; off >>= 1) sm += __shfl_xor(sm, off, 32);
        if (ln == 0) { smx[h] = mx; sinv[h] = 1.f / fmaxf(sm, 1e-16f); sed[h] = edn; }
    }
    __syncthreads();

    const int k  = tid & 63;
    const int hh = tid >> 6;
    float acc = 0.f;

    for (int e0 = 0; e0 < deg; e0 += 64) {
        int ce = min(64, deg - e0);
        __syncthreads();
        if (tid < ce * 4) {
            int e = tid >> 2, h = tid & 3;
            int s = clampi(ss[r0 + e0 + e], 0, N_NODES - 1);
            float w = es[s * 4 + h] + sed[h];
            w = (w > 0.f) ? w : 0.2f * w;
            sal[e * 4 + h] = expf(w - smx[h]) * sinv[h];
            if (h == 0) ssrc[e] = s;
        }
        __syncthreads();
        for (int e = 0; e < ce; ++e) {
            int s = ssrc[e];
            float xv = (float)A2[(size_t)s * KA + 256 + k];
            acc += sal[e * 4 + hh] * xv;
        }
    }
    A2[(size_t)n * KA + hh * 64 + k] = (bf16)acc;
}

// layers 2/3 logits on h (wave per node)
template <int H, int C>
__global__ __launch_bounds__(256) void k_logits(const bf16* __restrict__ G,
                                                const bf16* __restrict__ as_,
                                                const bf16* __restrict__ ad_,
                                                float* __restrict__ es, float* __restrict__ ed)
{
    const int wave = threadIdx.x >> 6;
    const int lane = threadIdx.x & 63;
    const int n = blockIdx.x * 4 + wave;
    if (n >= N_NODES) return;

#pragma unroll
    for (int h = 0; h < H; ++h) {
        float s = 0.f, d = 0.f;
        if constexpr (C == 256) {
            bf16x4 g  = *(const bf16x4*)(G + (size_t)n * SG + h * 256 + lane * 4);
            bf16x4 av = *(const bf16x4*)(as_ + h * 256 + lane * 4);
            bf16x4 dv = *(const bf16x4*)(ad_ + h * 256 + lane * 4);
#pragma unroll
            for (int j = 0; j < 4; ++j) {
                float gv = (float)g[j];
                s += gv * (float)av[j];
                d += gv * (float)dv[j];
            }
        } else {
            for (int c = lane; c < C; c += 64) {
                float hv = (float)G[(size_t)n * SG + h * C + c];
                s += hv * (float)as_[h * C + c];
                d += hv * (float)ad_[h * C + c];
            }
        }
#pragma unroll
        for (int off = 32; off; off >>= 1) {
            s += __shfl_xor(s, off);
            d += __shfl_xor(d, off);
        }
        if (lane == 0) { es[n * H + h] = s; ed[n * H + h] = d; }
    }
}

// Fused per-dst-node softmax + gather-aggregate + bias + skip (+mean/ELU).
// Phase 2: 4-wide edge grouping (measured optimum: VGPR 20, occ ~80%).
template <int H, int C, bool MEAN, bool ELU, bool EXTOUT>
__global__ __launch_bounds__(256) void k_agg(const bf16* __restrict__ G,
                                             const bf16* __restrict__ S,
                                             const float* __restrict__ es,
                                             const float* __restrict__ ed,
                                             const int* __restrict__ rp,
                                             const int* __restrict__ ss,
                                             const bf16* __restrict__ bgat,
                                             const bf16* __restrict__ bskip,
                                             void* __restrict__ out, int sout,
                                             const int* __restrict__ flags)
{
    constexpr int D  = H * C;
    constexpr int NV = (D + 3) / 4;
    constexpr int CH = 256;
    __shared__ float smx[H], sinv[H], sed[H];
    __shared__ float sal[CH * H];
    __shared__ int   ssrc[CH];

    const int n   = blockIdx.x;
    const int tid = threadIdx.x;
    int r0 = clampi(rp[n], 0, E2);
    int r1 = clampi(rp[n + 1], r0, E2);
    const int deg = r1 - r0;

    const int sw = tid >> 5, ln = tid & 31;
    for (int h = sw; h < H; h += 8) {
        float edn = ed[n * H + h];
        float mx = -1e30f;
        for (int e = ln; e < deg; e += 32) {
            int s = clampi(ss[r0 + e], 0, N_NODES - 1);
            float w = es[s * H + h] + edn;
            w = (w > 0.f) ? w : 0.2f * w;
            mx = fmaxf(mx, w);
        }
#pragma unroll
        for (int off = 16; off; off >>= 1) mx = fmaxf(mx, __shfl_xor(mx, off, 32));
        float sm = 0.f;
        for (int e = ln; e < deg; e += 32) {
            int s = clampi(ss[r0 + e], 0, N_NODES - 1);
            float w = es[s * H + h] + edn;
            w = (w > 0.f) ? w : 0.2f * w;
            sm += expf(w - mx);
        }
#pragma unroll
        for (int off = 16; off; off >>= 1) sm += __shfl_xor(sm, off, 32);
        if (ln == 0) { smx[h] = mx; sinv[h] = 1.f / fmaxf(sm, 1e-16f); sed[h] = edn; }
    }
    __syncthreads();

    const int c0 = tid * 4;
    const int hA = (c0 < D) ? (c0 / C) : 0;
    const int hB = (c0 + 3 < D) ? ((c0 + 3) / C) : hA;
    int hj1 = ((c0 + 1 < D) ? ((c0 + 1) / C) : hA) == hA;
    int hj2 = ((c0 + 2 < D) ? ((c0 + 2) / C) : hA) == hA;
    const bool active = (tid < NV);

    float acc[4] = {0.f, 0.f, 0.f, 0.f};

    for (int e0 = 0; e0 < deg; e0 += CH) {
        int ce = min(CH, deg - e0);
        __syncthreads();
        for (int t = tid; t < ce * H; t += 256) {
            int e = t / H, h = t - e * H;
            int s = clampi(ss[r0 + e0 + e], 0, N_NODES - 1);
            float w = es[s * H + h] + sed[h];
            w = (w > 0.f) ? w : 0.2f * w;
            sal[e * H + h] = expf(w - smx[h]) * sinv[h];
            if (h == 0) ssrc[e] = s;
        }
        __syncthreads();
        if (active) {
            for (int eb = 0; eb < ce; eb += 4) {
                int idx[4]; float zm[4];
#pragma unroll
                for (int p = 0; p < 4; ++p) {
                    int e = eb + p;
                    idx[p] = (e < ce) ? e : eb;
                    zm[p]  = (e < ce) ? 1.f : 0.f;
                }
                int sg[4];
#pragma unroll
                for (int p = 0; p < 4; ++p) sg[p] = ssrc[idx[p]];
                bf16x4 g[4];
#pragma unroll
                for (int p = 0; p < 4; ++p)
                    g[p] = *(const bf16x4*)(G + (size_t)sg[p] * SG + c0);
                if constexpr (C % 4 == 0) {
                    float a[4];
#pragma unroll
                    for (int p = 0; p < 4; ++p) a[p] = sal[idx[p] * H + hA] * zm[p];
#pragma unroll
                    for (int p = 0; p < 4; ++p)
#pragma unroll
                        for (int j = 0; j < 4; ++j)
                            acc[j] += a[p] * (float)g[p][j];
                } else {
                    float aL[4], aH[4];
#pragma unroll
                    for (int p = 0; p < 4; ++p) {
                        aL[p] = sal[idx[p] * H + hA] * zm[p];
                        aH[p] = sal[idx[p] * H + hB] * zm[p];
                    }
#pragma unroll
                    for (int p = 0; p < 4; ++p) {
                        acc[0] += aL[p] * (float)g[p][0];
                        acc[1] += (hj1 ? aL[p] : aH[p]) * (float)g[p][1];
                        acc[2] += (hj2 ? aL[p] : aH[p]) * (float)g[p][2];
                        acc[3] += aH[p] * (float)g[p][3];
                    }
                }
            }
        }
    }

    const int outbf = EXTOUT ? flags[1] : 1;

    if constexpr (!MEAN) {
        if (active) {
            bf16x4 bg = *(const bf16x4*)(bgat + c0);
            bf16x4 sk = *(const bf16x4*)(S + (size_t)n * SG + c0);
            bf16x4 bs = *(const bf16x4*)(bskip + c0);
            bf16x4 ov;
#pragma unroll
            for (int j = 0; j < 4; ++j) {
                float v = acc[j] + (float)bg[j] + (float)sk[j] + (float)bs[j];
                if (ELU) v = (v > 0.f) ? v : (expf(v) - 1.f);
                ov[j] = (bf16)v;
            }
            *(bf16x4*)((bf16*)out + (size_t)n * sout + c0) = ov;
        }
    } else {
        __shared__ float sagg[D];
        if (active) {
#pragma unroll
            for (int j = 0; j < 4; ++j) {
                int c = c0 + j;
                if (c < D) sagg[c] = acc[j];
            }
        }
        __syncthreads();
        for (int c = tid; c < C; c += 256) {
            float v = 0.f;
#pragma unroll
            for (int h = 0; h < H; ++h) v += sagg[h * C + c];
            v *= (1.f / H);
            v += (float)bgat[c] + (float)S[(size_t)n * SG + c] + (float)bskip[c];
            if (outbf) ((bf16*)out)[(size_t)n * sout + c] = (bf16)v;
            else       ((float*)out)[(size_t)n * sout + c] = v;
        }
    }
}

// ----------------------------------------------------------------- launch ---
extern "C" void kernel_launch(void* const* d_in, const int* in_sizes, int n_in,
                              void* d_out, int out_size, void* d_ws, size_t ws_size,
                              hipStream_t stream)
{
    const void* x   = d_in[0];
    const int*  ei  = (const int*)d_in[1];
    const void* W1  = d_in[2];
    const void* Wl1 = d_in[6];
    const void* W2  = d_in[8];
    const void* Wl2 = d_in[12];
    const void* W3  = d_in[14];
    const void* Wl3 = d_in[18];

    P12 ps;
    ps.s[0] = d_in[3];  ps.s[1] = d_in[4];  ps.s[2] = d_in[5];  ps.s[3] = d_in[7];
    ps.s[4] = d_in[9];  ps.s[5] = d_in[10]; ps.s[6] = d_in[11]; ps.s[7] = d_in[13];
    ps.s[8] = d_in[15]; ps.s[9] = d_in[16]; ps.s[10] = d_in[17]; ps.s[11] = d_in[19];

    char* w = (char*)d_ws;
    auto alloc = [&](size_t bytes) {
        char* p = w;
        w += (bytes + 255) & ~(size_t)255;
        return p;
    };
    int*   flags = (int*)alloc(64);
    int*   cnt   = (int*)alloc((size_t)N_NODES * 4);
    int*   rp    = (int*)alloc((size_t)(N_NODES + 1) * 4);
    int*   cur   = (int*)alloc((size_t)N_NODES * 4);
    int*   ss    = (int*)alloc((size_t)E2 * 4);
    float* es    = (float*)alloc((size_t)N_NODES * 6 * 4);
    float* ed    = (float*)alloc((size_t)N_NODES * 6 * 4);
    bf16*  pool  = (bf16*)alloc((size_t)PO_END * 2);
    float* ws1   = (float*)alloc((size_t)64 * 4 * 4);
    float* wd1   = (float*)alloc((size_t)64 * 4 * 4);
    bf16*  bsum  = (bf16*)alloc((size_t)D1 * 2);
    bf16*  BtL1  = (bf16*)alloc((size_t)D1 * KA * 2);        // layer-1 fused W^T
    bf16*  Bt2   = (bf16*)alloc((size_t)NP12 * 1024 * 2);    // layer-2 W^T
    bf16*  Bt3   = (bf16*)alloc((size_t)NP3 * 1024 * 2);     // layer-3 W^T
    bf16*  X     = (bf16*)alloc((size_t)N_NODES * D1 * 2);   // x1/x2
    bf16*  WS    = (bf16*)alloc((size_t)N_NODES * SG * 2);   // GEMM out [gat|skip]
    bf16*  A2    = WS;   // layer-1 A'' [N x KA] aliases WS (dead during layer 1)

    const dim3 blk(256);
    const int MT = (N_NODES + 127) / 128;   // 157

    // detect + cnt zero (1 launch)
    k_detect<<<(N_NODES + 255) / 256, 256, 0, stream>>>(
        ei, (const unsigned short*)x, flags, cnt);

    // CSR build
    k_count<<<(E2 + 255) / 256, 256, 0, stream>>>(ei, cnt, flags);
    k_scan<<<1, 256, 0, stream>>>(cnt, rp, cur);
    k_fill<<<(E2 + 255) / 256, 256, 0, stream>>>(ei, cur, ss, flags);

    // mega-prep: params + veca + padx + wfuse1 (1 launch)
    k_prep<<<PB_TOTAL, blk, 0, stream>>>(ps, pool, x, W1, Wl1, ws1, wd1, bsum,
                                         A2, BtL1, flags);
    // both weight transposes (1 launch)
    k_wcat2<<<dim3(16, 32 + NP3 / 64), blk, 0, stream>>>(W2, Wl2, W3, Wl3, Bt2, Bt3, flags);

    // ---- layer 1 (restructured): aggregate x, then fused GEMM K=320
    k_logits1<<<N_NODES / 4, 256, 0, stream>>>(A2, ws1, wd1, es, ed);
    k_aggx<<<N_NODES, 256, 0, stream>>>(A2, es, ed, rp, ss);
    k_gemm<true><<<MT * (D1 / 128), blk, 0, stream>>>(A2, BtL1, X, N_NODES, KA, KA, KA, D1,
                                                      MT, D1 / 128, bsum);   // x1 = ELU(...)

    // ---- layer 2: K=1024, out 2048 = [GAT 1024 | skip 1024]
    k_gemm<false><<<MT * (NP12 / 128), blk, 0, stream>>>(X, Bt2, WS, N_NODES, 1024, 1024, 1024, SG,
                                                         MT, NP12 / 128, nullptr);
    k_logits<4, 256><<<N_NODES / 4, 256, 0, stream>>>(WS, pool + PO_A2S, pool + PO_A2D, es, ed);
    k_agg<4, 256, false, true, false><<<N_NODES, 256, 0, stream>>>(
        WS, WS + D1, es, ed, rp, ss, pool + PO_B2, pool + PO_BL2, X, D1, flags);

    // ---- layer 3: K=1024, out 896 = [GAT 726 | skip 121 | pad]
    k_gemm<false><<<MT * (NP3 / 128), blk, 0, stream>>>(X, Bt3, WS, N_NODES, 1024, 1024, 1024, SG,
                                                        MT, NP3 / 128, nullptr);
    k_logits<6, 121><<<N_NODES / 4, 256, 0, stream>>>(WS, pool + PO_A3S, pool + PO_A3D, es, ed);
    k_agg<6, 121, true, false, true><<<N_NODES, 256, 0, stream>>>(
        WS, WS + 726, es, ed, rp, ss, pool + PO_B3, pool + PO_BL3, d_out, 121, flags);
}